// Round 1
// baseline (255.859 us; speedup 1.0000x reference)
//
#include <hip/hip_runtime.h>
#include <cstdint>
#include <cstddef>

// ---------------------------------------------------------------------------
// GCN 2-layer, N=100k nodes, E=1.6M edges, F=64, fp32 in/out.
//
//   dis[n] = rsqrt(in_deg[n]+1)            (self-loop folded in analytically)
//   g = bf16( (X @ W1) * dis[row] )        GEMM via MFMA, split-bf16 x3
//   h = relu( dis * (gather-sum g) + b1 )  per-node, fully in registers
//   g' = bf16( (h @ W2) * dis )            FUSED into agg1 epilogue (VALU fp32,
//                                           broadcast-h over 8-lane group)
//   out = dis * (gather-sum g') + b2
//
// CSR build: one-level bucketed counting sort into PADDED bucket windows
// (512 nodes/bucket, CAP=12288 slots; mean fill 8192, sigma~90 -> 45-sigma
// margin). No global histogram / scan / memset needed: each scatter block
// reserves chunks with atomicAdd on gcursor[b] (init'd to b*CAP).
// ---------------------------------------------------------------------------

#define BK_SHIFT 9                 // 512 nodes per bucket
#define BK_NODES 512
#define EPB 8192                   // edges per scatter block
#define CAP 12288                  // padded bucket capacity (slots)
#define NBMAX 256                  // max buckets (N<=131072 -> NB<=256)

typedef short bf16x8 __attribute__((ext_vector_type(8)));
typedef float f32x4  __attribute__((ext_vector_type(4)));

static __device__ __forceinline__ unsigned short f2b(float f) {
    unsigned x = __float_as_uint(f);
    unsigned r = (x + 0x7FFFu + ((x >> 16) & 1u)) >> 16;   // RNE
    return (unsigned short)r;
}
static __device__ __forceinline__ float blo(unsigned u) {
    return __uint_as_float(u << 16);
}
static __device__ __forceinline__ float bhi(unsigned u) {
    return __uint_as_float(u & 0xFFFF0000u);
}
static __device__ __forceinline__ void splitbf(float x, short& hi, short& lo) {
    unsigned short h = f2b(x);
    hi = (short)h;
    float r = x - __uint_as_float((unsigned)h << 16);
    lo = (short)f2b(r);
}

// ---- init: gcursor[b] = b*CAP --------------------------------------------
__global__ void k_init(int* __restrict__ gcursor, int NB) {
    int t = threadIdx.x;
    if (t < NB) gcursor[t] = t * CAP;
}

// ---- scatter edges into padded bucket windows, packed uint32 --------------
// pack = src (17 bits) | dst_local (9 bits) << 17   (N <= 131072)
// Assumes E % 4 == 0 (E=1.6M). 8192 edges/block; loads batched for ILP.
__global__ void __launch_bounds__(256) k_bscatter(const int* __restrict__ src,
                                                  const int* __restrict__ dst,
                                                  int* __restrict__ gcursor,
                                                  unsigned* __restrict__ packed,
                                                  int E, int NB) {
    __shared__ int hist[NBMAX];
    __shared__ int base[NBMAX];
    int t = threadIdx.x;
    for (int i = t; i < NB; i += 256) hist[i] = 0;
    __syncthreads();
    int e0 = blockIdx.x * EPB;
    int e1 = min(e0 + EPB, E);
    // phase 1: block histogram (8 int4 loads batched, then atomics)
    int4 dv[8];
    int kd[8];
#pragma unroll
    for (int k = 0; k < 8; ++k) {
        int e = e0 + t * 4 + k * 1024;
        kd[k] = (e + 3 < e1) ? 1 : 0;
        if (kd[k]) dv[k] = *(const int4*)(dst + e);
    }
#pragma unroll
    for (int k = 0; k < 8; ++k) {
        if (kd[k]) {
            atomicAdd(&hist[dv[k].x >> BK_SHIFT], 1);
            atomicAdd(&hist[dv[k].y >> BK_SHIFT], 1);
            atomicAdd(&hist[dv[k].z >> BK_SHIFT], 1);
            atomicAdd(&hist[dv[k].w >> BK_SHIFT], 1);
        }
    }
    __syncthreads();
    // phase 2: reserve chunk in each bucket's padded window
    for (int i = t; i < NB; i += 256) {
        int c = hist[i];
        base[i] = c ? atomicAdd(&gcursor[i], c) : 0;
        hist[i] = 0;
    }
    __syncthreads();
    // phase 3: scatter (batched src loads; dst re-used from regs)
    int4 sv[8];
#pragma unroll
    for (int k = 0; k < 8; ++k) {
        int e = e0 + t * 4 + k * 1024;
        if (kd[k]) sv[k] = *(const int4*)(src + e);
    }
#pragma unroll
    for (int k = 0; k < 8; ++k) {
        if (kd[k]) {
            int b0 = dv[k].x >> BK_SHIFT;
            int p0 = base[b0] + atomicAdd(&hist[b0], 1);
            packed[p0] = (unsigned)sv[k].x | (((unsigned)dv[k].x & (BK_NODES - 1)) << 17);
            int b1 = dv[k].y >> BK_SHIFT;
            int p1 = base[b1] + atomicAdd(&hist[b1], 1);
            packed[p1] = (unsigned)sv[k].y | (((unsigned)dv[k].y & (BK_NODES - 1)) << 17);
            int b2 = dv[k].z >> BK_SHIFT;
            int p2 = base[b2] + atomicAdd(&hist[b2], 1);
            packed[p2] = (unsigned)sv[k].z | (((unsigned)dv[k].z & (BK_NODES - 1)) << 17);
            int b3 = dv[k].w >> BK_SHIFT;
            int p3 = base[b3] + atomicAdd(&hist[b3], 1);
            packed[p3] = (unsigned)sv[k].w | (((unsigned)dv[k].w & (BK_NODES - 1)) << 17);
        }
    }
}

// ---- per-bucket CSR build (one block of 512 per bucket) -------------------
__global__ void __launch_bounds__(512) k_build(const unsigned* __restrict__ packed,
                                               const int* __restrict__ gcursor,
                                               int* __restrict__ rp,
                                               int* __restrict__ dega,
                                               float* __restrict__ dis,
                                               int* __restrict__ col, int N) {
    __shared__ int cnt_s[BK_NODES];
    __shared__ int tmp[BK_NODES];
    int b = blockIdx.x;
    int t = threadIdx.x;
    int node0 = b << BK_SHIFT;
    int nnode = min(BK_NODES, N - node0);
    int e0 = b * CAP;
    int e1 = gcursor[b];               // final cursor = e0 + count
    cnt_s[t] = 0;
    __syncthreads();
    for (int e = e0 + t * 4; e < e1; e += 2048) {
        int m = e1 - e; m = m > 4 ? 4 : m;
        unsigned p0 = packed[e];
        unsigned p1 = (m > 1) ? packed[e + 1] : 0;
        unsigned p2 = (m > 2) ? packed[e + 2] : 0;
        unsigned p3 = (m > 3) ? packed[e + 3] : 0;
        atomicAdd(&cnt_s[p0 >> 17], 1);
        if (m > 1) atomicAdd(&cnt_s[p1 >> 17], 1);
        if (m > 2) atomicAdd(&cnt_s[p2 >> 17], 1);
        if (m > 3) atomicAdd(&cnt_s[p3 >> 17], 1);
    }
    __syncthreads();
    int v = cnt_s[t];
    tmp[t] = v;
    __syncthreads();
    for (int off = 1; off < BK_NODES; off <<= 1) {
        int a = (t >= off) ? tmp[t - off] : 0;
        __syncthreads();
        tmp[t] += a;
        __syncthreads();
    }
    int excl = tmp[t] - v;
    if (t < nnode) {
        rp[node0 + t] = e0 + excl;
        dega[node0 + t] = v;
        dis[node0 + t] = rsqrtf((float)(v + 1));
    }
    __syncthreads();
    cnt_s[t] = excl;                   // reuse as local cursor
    __syncthreads();
    for (int e = e0 + t * 4; e < e1; e += 2048) {
        int m = e1 - e; m = m > 4 ? 4 : m;
        unsigned p0 = packed[e];
        unsigned p1 = (m > 1) ? packed[e + 1] : 0;
        unsigned p2 = (m > 2) ? packed[e + 2] : 0;
        unsigned p3 = (m > 3) ? packed[e + 3] : 0;
        int pos0 = atomicAdd(&cnt_s[p0 >> 17], 1);
        col[e0 + pos0] = (int)(p0 & 0x1FFFFu);
        if (m > 1) { int pos = atomicAdd(&cnt_s[p1 >> 17], 1); col[e0 + pos] = (int)(p1 & 0x1FFFFu); }
        if (m > 2) { int pos = atomicAdd(&cnt_s[p2 >> 17], 1); col[e0 + pos] = (int)(p2 & 0x1FFFFu); }
        if (m > 3) { int pos = atomicAdd(&cnt_s[p3 >> 17], 1); col[e0 + pos] = (int)(p3 & 0x1FFFFu); }
    }
}

// ---- GEMM via MFMA: g16[row] = bf16( (X[row] @ W) * dis[row] ) ------------
// Layouts (measured, learn_hip m89/m91/m120):
//   A[m=lane&15][k=quad*8+j]   B[k=quad*8+j][n=lane&15]
//   C: col=lane&15, row=quad*4+reg
__global__ void __launch_bounds__(256) k_gemm_mfma(const float* __restrict__ X,
                                                   const float* __restrict__ W,
                                                   const float* __restrict__ dis,
                                                   unsigned short* __restrict__ g16,
                                                   int n, int nstrips) {
    __shared__ float Ws[4096];     // 64x64 fp32 = 16 KB
    int t = threadIdx.x;
    {
        const float4* W4 = (const float4*)W;
        float4* S4 = (float4*)Ws;
#pragma unroll
        for (int i = 0; i < 4; ++i) S4[t + i * 256] = W4[t + i * 256];
    }
    __syncthreads();
    int wid  = t >> 6;
    int lane = t & 63;
    int quad = lane >> 4;
    int fl   = lane & 15;

    bf16x8 Bh[4][2], Bl[4][2];
#pragma unroll
    for (int tt = 0; tt < 4; ++tt)
#pragma unroll
        for (int c = 0; c < 2; ++c)
#pragma unroll
            for (int j = 0; j < 8; ++j) {
                float w = Ws[(c * 32 + quad * 8 + j) * 64 + tt * 16 + fl];
                short hi, lo;
                splitbf(w, hi, lo);
                Bh[tt][c][j] = hi;
                Bl[tt][c][j] = lo;
            }

    for (int s = blockIdx.x * 4 + wid; s < nstrips; s += gridDim.x * 4) {
        int row0 = s << 4;
        const float4* xp = (const float4*)(X + ((size_t)(row0 + fl) << 6));
        bf16x8 Ah[2], Al[2];
#pragma unroll
        for (int c = 0; c < 2; ++c) {
            float4 a = xp[c * 8 + quad * 2];
            float4 b = xp[c * 8 + quad * 2 + 1];
            float xs[8] = {a.x, a.y, a.z, a.w, b.x, b.y, b.z, b.w};
#pragma unroll
            for (int j = 0; j < 8; ++j) {
                short hi, lo;
                splitbf(xs[j], hi, lo);
                Ah[c][j] = hi;
                Al[c][j] = lo;
            }
        }
        f32x4 acc[4];
#pragma unroll
        for (int tt = 0; tt < 4; ++tt) acc[tt] = (f32x4){0.f, 0.f, 0.f, 0.f};
#pragma unroll
        for (int tt = 0; tt < 4; ++tt) {
#pragma unroll
            for (int c = 0; c < 2; ++c) {
                acc[tt] = __builtin_amdgcn_mfma_f32_16x16x32_bf16(Ah[c], Bh[tt][c], acc[tt], 0, 0, 0);
                acc[tt] = __builtin_amdgcn_mfma_f32_16x16x32_bf16(Al[c], Bh[tt][c], acc[tt], 0, 0, 0);
                acc[tt] = __builtin_amdgcn_mfma_f32_16x16x32_bf16(Ah[c], Bl[tt][c], acc[tt], 0, 0, 0);
            }
        }
        float4 dv = *(const float4*)(dis + row0 + quad * 4);
        float ds4[4] = {dv.x, dv.y, dv.z, dv.w};
#pragma unroll
        for (int tt = 0; tt < 4; ++tt) {
#pragma unroll
            for (int r = 0; r < 4; ++r) {
                int row = row0 + quad * 4 + r;
                float v = acc[tt][r] * ds4[r];
                g16[(size_t)row * 64 + tt * 16 + fl] = f2b(v);
            }
        }
    }
}

// ---- Aggregate: 8 nodes/wave, 8 lanes x uint4 per node, 8 loads in flight -
template <int RELU>
__global__ void __launch_bounds__(256) k_agg(const unsigned short* __restrict__ g16,
                                             const int* __restrict__ col,
                                             const int* __restrict__ rp,
                                             const int* __restrict__ dega,
                                             const float* __restrict__ dis,
                                             const float* __restrict__ bias,
                                             float* __restrict__ out, int n) {
    int lane = threadIdx.x & 63;
    int wv = (blockIdx.x << 2) | (threadIdx.x >> 6);   // global wave id
    int sub = lane >> 3;               // 0..7 : node within wave
    int fl  = lane & 7;                // 0..7 : 8-feat group
    int base = wv << 3;
    if (base >= n) return;             // wave-uniform
    int node = base + sub;
    int nd = min(node, n - 1);
    int start = rp[nd];
    int deg = (node < n) ? dega[nd] : 0;
    int dm = max(deg, __shfl_xor(deg, 8));
    dm = max(dm, __shfl_xor(dm, 16));
    dm = max(dm, __shfl_xor(dm, 32));  // wave max deg

    uint4 us = *((const uint4*)(g16 + ((size_t)nd << 6)) + fl);   // self row
    float A[8], B[8], C[8], D[8];
    A[0] = blo(us.x); A[1] = bhi(us.x); A[2] = blo(us.y); A[3] = bhi(us.y);
    A[4] = blo(us.z); A[5] = bhi(us.z); A[6] = blo(us.w); A[7] = bhi(us.w);
#pragma unroll
    for (int j = 0; j < 8; ++j) { B[j] = 0.f; C[j] = 0.f; D[j] = 0.f; }

    int sb = sub << 3;
    for (int c = 0; c < dm; c += 8) {
        int rem = deg - c;
        int cv = 0;
        if (fl < rem) cv = col[start + c + fl];
        int rr[8];
#pragma unroll
        for (int i = 0; i < 8; ++i) rr[i] = __shfl(cv, sb + i);
        uint4 u[8];
#pragma unroll
        for (int i = 0; i < 8; ++i)
            if (i < rem) u[i] = *((const uint4*)(g16 + ((size_t)rr[i] << 6)) + fl);
#pragma unroll
        for (int i = 0; i < 8; ++i) {
            if (i < rem) {
                float* T = ((i & 3) == 0) ? A : ((i & 3) == 1) ? B : ((i & 3) == 2) ? C : D;
                T[0] += blo(u[i].x); T[1] += bhi(u[i].x);
                T[2] += blo(u[i].y); T[3] += bhi(u[i].y);
                T[4] += blo(u[i].z); T[5] += bhi(u[i].z);
                T[6] += blo(u[i].w); T[7] += bhi(u[i].w);
            }
        }
    }
    float s = dis[nd];
    float4 bv0 = ((const float4*)bias)[fl * 2];
    float4 bv1 = ((const float4*)bias)[fl * 2 + 1];
    float r[8];
#pragma unroll
    for (int j = 0; j < 8; ++j) r[j] = (A[j] + B[j]) + (C[j] + D[j]);
    float4 o0, o1;
    o0.x = fmaf(s, r[0], bv0.x); o0.y = fmaf(s, r[1], bv0.y);
    o0.z = fmaf(s, r[2], bv0.z); o0.w = fmaf(s, r[3], bv0.w);
    o1.x = fmaf(s, r[4], bv1.x); o1.y = fmaf(s, r[5], bv1.y);
    o1.z = fmaf(s, r[6], bv1.z); o1.w = fmaf(s, r[7], bv1.w);
    if (RELU) {
        o0.x = fmaxf(o0.x, 0.f); o0.y = fmaxf(o0.y, 0.f);
        o0.z = fmaxf(o0.z, 0.f); o0.w = fmaxf(o0.w, 0.f);
        o1.x = fmaxf(o1.x, 0.f); o1.y = fmaxf(o1.y, 0.f);
        o1.z = fmaxf(o1.z, 0.f); o1.w = fmaxf(o1.w, 0.f);
    }
    if (node < n) {
        float4* op = (float4*)(out + ((size_t)node << 6)) + fl * 2;
        op[0] = o0;
        op[1] = o1;
    }
}

// ---- Fused aggregate(L1) + relu + VALU GEMM (h @ W2) * dis -> bf16 --------
// Same gather structure as k_agg<1>, but instead of writing h to HBM, the
// epilogue computes g16out[node] = bf16( (relu(dis*agg+b1) @ W2) * dis )
// entirely in registers: the 8-lane group owning a node broadcasts its 64
// h-feats via __shfl, each lane accumulates its own 8 output features from
// W2 staged in LDS (16 KB). Saves the 25.6 MB h write + 25.6 MB h read and
// the entire layer-2 MFMA dispatch. All register indices are compile-time
// (rule #20: no runtime-indexed arrays -> no scratch).
__global__ void __launch_bounds__(256) k_agg_gemm(const unsigned short* __restrict__ g16,
                                                  const int* __restrict__ col,
                                                  const int* __restrict__ rp,
                                                  const int* __restrict__ dega,
                                                  const float* __restrict__ dis,
                                                  const float* __restrict__ bias,
                                                  const float* __restrict__ W2,
                                                  unsigned short* __restrict__ g16out,
                                                  int n) {
    __shared__ float W2s[4096];        // 64x64 fp32 = 16 KB
    int t = threadIdx.x;
    {
        const float4* W4 = (const float4*)W2;
        float4* S4 = (float4*)W2s;
#pragma unroll
        for (int i = 0; i < 4; ++i) S4[t + i * 256] = W4[t + i * 256];
    }
    __syncthreads();                   // all waves reach this before any exit

    int lane = t & 63;
    int wv = (blockIdx.x << 2) | (t >> 6);
    int sub = lane >> 3;
    int fl  = lane & 7;
    int base = wv << 3;
    if (base >= n) return;             // wave-uniform, after the only sync
    int node = base + sub;
    int nd = min(node, n - 1);
    int start = rp[nd];
    int deg = (node < n) ? dega[nd] : 0;
    int dm = max(deg, __shfl_xor(deg, 8));
    dm = max(dm, __shfl_xor(dm, 16));
    dm = max(dm, __shfl_xor(dm, 32));

    uint4 us = *((const uint4*)(g16 + ((size_t)nd << 6)) + fl);   // self row
    float A[8], B[8], C[8], D[8];
    A[0] = blo(us.x); A[1] = bhi(us.x); A[2] = blo(us.y); A[3] = bhi(us.y);
    A[4] = blo(us.z); A[5] = bhi(us.z); A[6] = blo(us.w); A[7] = bhi(us.w);
#pragma unroll
    for (int j = 0; j < 8; ++j) { B[j] = 0.f; C[j] = 0.f; D[j] = 0.f; }

    int sb = sub << 3;
    for (int c = 0; c < dm; c += 8) {
        int rem = deg - c;
        int cv = 0;
        if (fl < rem) cv = col[start + c + fl];
        int rr[8];
#pragma unroll
        for (int i = 0; i < 8; ++i) rr[i] = __shfl(cv, sb + i);
        uint4 u[8];
#pragma unroll
        for (int i = 0; i < 8; ++i)
            if (i < rem) u[i] = *((const uint4*)(g16 + ((size_t)rr[i] << 6)) + fl);
#pragma unroll
        for (int i = 0; i < 8; ++i) {
            if (i < rem) {
                float* T = ((i & 3) == 0) ? A : ((i & 3) == 1) ? B : ((i & 3) == 2) ? C : D;
                T[0] += blo(u[i].x); T[1] += bhi(u[i].x);
                T[2] += blo(u[i].y); T[3] += bhi(u[i].y);
                T[4] += blo(u[i].z); T[5] += bhi(u[i].z);
                T[6] += blo(u[i].w); T[7] += bhi(u[i].w);
            }
        }
    }
    // h = relu(dis*agg + b1), this lane holds feats fl*8 .. fl*8+7 of node
    float s = dis[nd];
    float4 bv0 = ((const float4*)bias)[fl * 2];
    float4 bv1 = ((const float4*)bias)[fl * 2 + 1];
    float r[8];
#pragma unroll
    for (int j = 0; j < 8; ++j) r[j] = (A[j] + B[j]) + (C[j] + D[j]);
    r[0] = fmaxf(fmaf(s, r[0], bv0.x), 0.f);
    r[1] = fmaxf(fmaf(s, r[1], bv0.y), 0.f);
    r[2] = fmaxf(fmaf(s, r[2], bv0.z), 0.f);
    r[3] = fmaxf(fmaf(s, r[3], bv0.w), 0.f);
    r[4] = fmaxf(fmaf(s, r[4], bv1.x), 0.f);
    r[5] = fmaxf(fmaf(s, r[5], bv1.y), 0.f);
    r[6] = fmaxf(fmaf(s, r[6], bv1.z), 0.f);
    r[7] = fmaxf(fmaf(s, r[7], bv1.w), 0.f);

    // out[j] = sum_k h[k] * W2[k][j], lane owns j = fl*8 .. fl*8+7
    float acc[8];
#pragma unroll
    for (int j = 0; j < 8; ++j) acc[j] = 0.f;
#pragma unroll
    for (int g = 0; g < 8; ++g) {
        float hk[8];                   // h[g*8+q], broadcast from lane sb+g
#pragma unroll
        for (int q = 0; q < 8; ++q) hk[q] = __shfl(r[q], sb + g);
#pragma unroll
        for (int q = 0; q < 8; ++q) {
            const float4* wp = (const float4*)&W2s[(g * 8 + q) * 64 + fl * 8];
            float4 wa = wp[0], wb = wp[1];
            acc[0] = fmaf(hk[q], wa.x, acc[0]);
            acc[1] = fmaf(hk[q], wa.y, acc[1]);
            acc[2] = fmaf(hk[q], wa.z, acc[2]);
            acc[3] = fmaf(hk[q], wa.w, acc[3]);
            acc[4] = fmaf(hk[q], wb.x, acc[4]);
            acc[5] = fmaf(hk[q], wb.y, acc[5]);
            acc[6] = fmaf(hk[q], wb.z, acc[6]);
            acc[7] = fmaf(hk[q], wb.w, acc[7]);
        }
    }
    if (node < n) {
        uint4 o;
        o.x = (unsigned)f2b(acc[0] * s) | ((unsigned)f2b(acc[1] * s) << 16);
        o.y = (unsigned)f2b(acc[2] * s) | ((unsigned)f2b(acc[3] * s) << 16);
        o.z = (unsigned)f2b(acc[4] * s) | ((unsigned)f2b(acc[5] * s) << 16);
        o.w = (unsigned)f2b(acc[6] * s) | ((unsigned)f2b(acc[7] * s) << 16);
        *((uint4*)(g16out + ((size_t)node << 6)) + fl) = o;
    }
}

extern "C" void kernel_launch(void* const* d_in, const int* in_sizes, int n_in,
                              void* d_out, int out_size, void* d_ws, size_t ws_size,
                              hipStream_t stream) {
    const float* x  = (const float*)d_in[0];
    const int*   ei = (const int*)d_in[1];
    const float* W1 = (const float*)d_in[2];
    const float* b1 = (const float*)d_in[3];
    const float* W2 = (const float*)d_in[4];
    const float* b2 = (const float*)d_in[5];
    float* out = (float*)d_out;

    const int N = in_sizes[0] / 64;
    const int E = in_sizes[1] / 2;
    const int NB = (N + BK_NODES - 1) >> BK_SHIFT;
    const int nstrips = (N + 15) >> 4;
    const int* src = ei;
    const int* dst = ei + E;

    char* ws = (char*)d_ws;
    size_t off = 0;
    auto alloc = [&](size_t bytes) -> void* {
        void* p = ws + off;
        off = (off + bytes + 255) & ~(size_t)255;
        return p;
    };
    int*            gcursor = (int*)alloc((size_t)NB * 4);
    int*            rp      = (int*)alloc((size_t)N * 4);
    int*            dega    = (int*)alloc((size_t)N * 4);
    float*          dis     = (float*)alloc((size_t)N * 4);
    unsigned*       packed  = (unsigned*)alloc((size_t)NB * CAP * 4);
    int*            col     = (int*)alloc((size_t)NB * CAP * 4);
    unsigned short* g16     = (unsigned short*)alloc((size_t)N * 64 * 2);
    unsigned short* g16b    = (unsigned short*)alloc((size_t)N * 64 * 2);
    (void)ws_size;

    k_init<<<1, 256, 0, stream>>>(gcursor, NB);
    k_bscatter<<<(E + EPB - 1) / EPB, 256, 0, stream>>>(src, dst, gcursor, packed, E, NB);
    k_build<<<NB, 512, 0, stream>>>(packed, gcursor, rp, dega, dis, col, N);

    // Layer 1 GEMM (MFMA), then fused agg1+relu+GEMM2 -> g16b, then agg2
    k_gemm_mfma<<<782, 256, 0, stream>>>(x, W1, dis, g16, N, nstrips);
    k_agg_gemm<<<(N + 31) / 32, 256, 0, stream>>>(g16, col, rp, dega, dis, b1, W2, g16b, N);
    k_agg<0><<<(N + 31) / 32, 256, 0, stream>>>(g16b, col, rp, dega, dis, b2, out, N);
}

// Round 2
// 208.366 us; speedup vs baseline: 1.2279x; 1.2279x over previous
//
#include <hip/hip_runtime.h>
#include <cstdint>
#include <cstddef>

// ---------------------------------------------------------------------------
// GCN 2-layer, N=100k nodes, E=1.6M edges, F=64, fp32 in/out.
//
//   dis[n] = rsqrt(in_deg[n]+1)            (self-loop folded in analytically)
//   g = bf16( (X @ W) * dis[row] )         GEMM via MFMA, split-bf16 x3
//   out[n] = dis[n] * ( sum_{e: dst=n} g[src(e)] + g[n] ) + b   (+ relu L1)
//
// CSR build: one-level bucketed counting sort into PADDED bucket windows
// (512 nodes/bucket, CAP=12288 slots; mean fill 8192, sigma~90 -> 45-sigma
// margin). No global histogram / scan / memset needed: each scatter block
// reserves chunks with atomicAdd on gcursor[b] (init'd to b*CAP).
//
// R2: aggregation is gather-LATENCY-bound (R1 counters: VALUBusy 23%, hbm 12%,
// MfmaUtil 0). k_agg now software-pipelines two 8-row gather batches (u0/u1,
// 8-16 loads in flight/wave vs 0-8) and slims accumulators A..D -> A,B
// (-16 VGPR) with __launch_bounds__(256,4) to hold 4 waves/SIMD.
// R1's fused GEMM2 epilogue reverted: VGPR 132 -> 3 waves/SIMD cost far more
// than the h round-trip it saved.
// ---------------------------------------------------------------------------

#define BK_SHIFT 9                 // 512 nodes per bucket
#define BK_NODES 512
#define EPB 8192                   // edges per scatter block
#define CAP 12288                  // padded bucket capacity (slots)
#define NBMAX 256                  // max buckets (N<=131072 -> NB<=256)

typedef short bf16x8 __attribute__((ext_vector_type(8)));
typedef float f32x4  __attribute__((ext_vector_type(4)));

static __device__ __forceinline__ unsigned short f2b(float f) {
    unsigned x = __float_as_uint(f);
    unsigned r = (x + 0x7FFFu + ((x >> 16) & 1u)) >> 16;   // RNE
    return (unsigned short)r;
}
static __device__ __forceinline__ float blo(unsigned u) {
    return __uint_as_float(u << 16);
}
static __device__ __forceinline__ float bhi(unsigned u) {
    return __uint_as_float(u & 0xFFFF0000u);
}
static __device__ __forceinline__ void splitbf(float x, short& hi, short& lo) {
    unsigned short h = f2b(x);
    hi = (short)h;
    float r = x - __uint_as_float((unsigned)h << 16);
    lo = (short)f2b(r);
}

// ---- init: gcursor[b] = b*CAP --------------------------------------------
__global__ void k_init(int* __restrict__ gcursor, int NB) {
    int t = threadIdx.x;
    if (t < NB) gcursor[t] = t * CAP;
}

// ---- scatter edges into padded bucket windows, packed uint32 --------------
// pack = src (17 bits) | dst_local (9 bits) << 17   (N <= 131072)
// Assumes E % 4 == 0 (E=1.6M). 8192 edges/block; loads batched for ILP.
__global__ void __launch_bounds__(256) k_bscatter(const int* __restrict__ src,
                                                  const int* __restrict__ dst,
                                                  int* __restrict__ gcursor,
                                                  unsigned* __restrict__ packed,
                                                  int E, int NB) {
    __shared__ int hist[NBMAX];
    __shared__ int base[NBMAX];
    int t = threadIdx.x;
    for (int i = t; i < NB; i += 256) hist[i] = 0;
    __syncthreads();
    int e0 = blockIdx.x * EPB;
    int e1 = min(e0 + EPB, E);
    // phase 1: block histogram (8 int4 loads batched, then atomics)
    int4 dv[8];
    int kd[8];
#pragma unroll
    for (int k = 0; k < 8; ++k) {
        int e = e0 + t * 4 + k * 1024;
        kd[k] = (e + 3 < e1) ? 1 : 0;
        if (kd[k]) dv[k] = *(const int4*)(dst + e);
    }
#pragma unroll
    for (int k = 0; k < 8; ++k) {
        if (kd[k]) {
            atomicAdd(&hist[dv[k].x >> BK_SHIFT], 1);
            atomicAdd(&hist[dv[k].y >> BK_SHIFT], 1);
            atomicAdd(&hist[dv[k].z >> BK_SHIFT], 1);
            atomicAdd(&hist[dv[k].w >> BK_SHIFT], 1);
        }
    }
    __syncthreads();
    // phase 2: reserve chunk in each bucket's padded window
    for (int i = t; i < NB; i += 256) {
        int c = hist[i];
        base[i] = c ? atomicAdd(&gcursor[i], c) : 0;
        hist[i] = 0;
    }
    __syncthreads();
    // phase 3: scatter (batched src loads; dst re-used from regs)
    int4 sv[8];
#pragma unroll
    for (int k = 0; k < 8; ++k) {
        int e = e0 + t * 4 + k * 1024;
        if (kd[k]) sv[k] = *(const int4*)(src + e);
    }
#pragma unroll
    for (int k = 0; k < 8; ++k) {
        if (kd[k]) {
            int b0 = dv[k].x >> BK_SHIFT;
            int p0 = base[b0] + atomicAdd(&hist[b0], 1);
            packed[p0] = (unsigned)sv[k].x | (((unsigned)dv[k].x & (BK_NODES - 1)) << 17);
            int b1 = dv[k].y >> BK_SHIFT;
            int p1 = base[b1] + atomicAdd(&hist[b1], 1);
            packed[p1] = (unsigned)sv[k].y | (((unsigned)dv[k].y & (BK_NODES - 1)) << 17);
            int b2 = dv[k].z >> BK_SHIFT;
            int p2 = base[b2] + atomicAdd(&hist[b2], 1);
            packed[p2] = (unsigned)sv[k].z | (((unsigned)dv[k].z & (BK_NODES - 1)) << 17);
            int b3 = dv[k].w >> BK_SHIFT;
            int p3 = base[b3] + atomicAdd(&hist[b3], 1);
            packed[p3] = (unsigned)sv[k].w | (((unsigned)dv[k].w & (BK_NODES - 1)) << 17);
        }
    }
}

// ---- per-bucket CSR build (one block of 512 per bucket) -------------------
__global__ void __launch_bounds__(512) k_build(const unsigned* __restrict__ packed,
                                               const int* __restrict__ gcursor,
                                               int* __restrict__ rp,
                                               int* __restrict__ dega,
                                               float* __restrict__ dis,
                                               int* __restrict__ col, int N) {
    __shared__ int cnt_s[BK_NODES];
    __shared__ int tmp[BK_NODES];
    int b = blockIdx.x;
    int t = threadIdx.x;
    int node0 = b << BK_SHIFT;
    int nnode = min(BK_NODES, N - node0);
    int e0 = b * CAP;
    int e1 = gcursor[b];               // final cursor = e0 + count
    cnt_s[t] = 0;
    __syncthreads();
    for (int e = e0 + t * 4; e < e1; e += 2048) {
        int m = e1 - e; m = m > 4 ? 4 : m;
        unsigned p0 = packed[e];
        unsigned p1 = (m > 1) ? packed[e + 1] : 0;
        unsigned p2 = (m > 2) ? packed[e + 2] : 0;
        unsigned p3 = (m > 3) ? packed[e + 3] : 0;
        atomicAdd(&cnt_s[p0 >> 17], 1);
        if (m > 1) atomicAdd(&cnt_s[p1 >> 17], 1);
        if (m > 2) atomicAdd(&cnt_s[p2 >> 17], 1);
        if (m > 3) atomicAdd(&cnt_s[p3 >> 17], 1);
    }
    __syncthreads();
    int v = cnt_s[t];
    tmp[t] = v;
    __syncthreads();
    for (int off = 1; off < BK_NODES; off <<= 1) {
        int a = (t >= off) ? tmp[t - off] : 0;
        __syncthreads();
        tmp[t] += a;
        __syncthreads();
    }
    int excl = tmp[t] - v;
    if (t < nnode) {
        rp[node0 + t] = e0 + excl;
        dega[node0 + t] = v;
        dis[node0 + t] = rsqrtf((float)(v + 1));
    }
    __syncthreads();
    cnt_s[t] = excl;                   // reuse as local cursor
    __syncthreads();
    for (int e = e0 + t * 4; e < e1; e += 2048) {
        int m = e1 - e; m = m > 4 ? 4 : m;
        unsigned p0 = packed[e];
        unsigned p1 = (m > 1) ? packed[e + 1] : 0;
        unsigned p2 = (m > 2) ? packed[e + 2] : 0;
        unsigned p3 = (m > 3) ? packed[e + 3] : 0;
        int pos0 = atomicAdd(&cnt_s[p0 >> 17], 1);
        col[e0 + pos0] = (int)(p0 & 0x1FFFFu);
        if (m > 1) { int pos = atomicAdd(&cnt_s[p1 >> 17], 1); col[e0 + pos] = (int)(p1 & 0x1FFFFu); }
        if (m > 2) { int pos = atomicAdd(&cnt_s[p2 >> 17], 1); col[e0 + pos] = (int)(p2 & 0x1FFFFu); }
        if (m > 3) { int pos = atomicAdd(&cnt_s[p3 >> 17], 1); col[e0 + pos] = (int)(p3 & 0x1FFFFu); }
    }
}

// ---- GEMM via MFMA: g16[row] = bf16( (X[row] @ W) * dis[row] ) ------------
// Layouts (measured, learn_hip m89/m91/m120):
//   A[m=lane&15][k=quad*8+j]   B[k=quad*8+j][n=lane&15]
//   C: col=lane&15, row=quad*4+reg
__global__ void __launch_bounds__(256) k_gemm_mfma(const float* __restrict__ X,
                                                   const float* __restrict__ W,
                                                   const float* __restrict__ dis,
                                                   unsigned short* __restrict__ g16,
                                                   int n, int nstrips) {
    __shared__ float Ws[4096];     // 64x64 fp32 = 16 KB
    int t = threadIdx.x;
    {
        const float4* W4 = (const float4*)W;
        float4* S4 = (float4*)Ws;
#pragma unroll
        for (int i = 0; i < 4; ++i) S4[t + i * 256] = W4[t + i * 256];
    }
    __syncthreads();
    int wid  = t >> 6;
    int lane = t & 63;
    int quad = lane >> 4;
    int fl   = lane & 15;

    bf16x8 Bh[4][2], Bl[4][2];
#pragma unroll
    for (int tt = 0; tt < 4; ++tt)
#pragma unroll
        for (int c = 0; c < 2; ++c)
#pragma unroll
            for (int j = 0; j < 8; ++j) {
                float w = Ws[(c * 32 + quad * 8 + j) * 64 + tt * 16 + fl];
                short hi, lo;
                splitbf(w, hi, lo);
                Bh[tt][c][j] = hi;
                Bl[tt][c][j] = lo;
            }

    for (int s = blockIdx.x * 4 + wid; s < nstrips; s += gridDim.x * 4) {
        int row0 = s << 4;
        const float4* xp = (const float4*)(X + ((size_t)(row0 + fl) << 6));
        bf16x8 Ah[2], Al[2];
#pragma unroll
        for (int c = 0; c < 2; ++c) {
            float4 a = xp[c * 8 + quad * 2];
            float4 b = xp[c * 8 + quad * 2 + 1];
            float xs[8] = {a.x, a.y, a.z, a.w, b.x, b.y, b.z, b.w};
#pragma unroll
            for (int j = 0; j < 8; ++j) {
                short hi, lo;
                splitbf(xs[j], hi, lo);
                Ah[c][j] = hi;
                Al[c][j] = lo;
            }
        }
        f32x4 acc[4];
#pragma unroll
        for (int tt = 0; tt < 4; ++tt) acc[tt] = (f32x4){0.f, 0.f, 0.f, 0.f};
#pragma unroll
        for (int tt = 0; tt < 4; ++tt) {
#pragma unroll
            for (int c = 0; c < 2; ++c) {
                acc[tt] = __builtin_amdgcn_mfma_f32_16x16x32_bf16(Ah[c], Bh[tt][c], acc[tt], 0, 0, 0);
                acc[tt] = __builtin_amdgcn_mfma_f32_16x16x32_bf16(Al[c], Bh[tt][c], acc[tt], 0, 0, 0);
                acc[tt] = __builtin_amdgcn_mfma_f32_16x16x32_bf16(Ah[c], Bl[tt][c], acc[tt], 0, 0, 0);
            }
        }
        float4 dv = *(const float4*)(dis + row0 + quad * 4);
        float ds4[4] = {dv.x, dv.y, dv.z, dv.w};
#pragma unroll
        for (int tt = 0; tt < 4; ++tt) {
#pragma unroll
            for (int r = 0; r < 4; ++r) {
                int row = row0 + quad * 4 + r;
                float v = acc[tt][r] * ds4[r];
                g16[(size_t)row * 64 + tt * 16 + fl] = f2b(v);
            }
        }
    }
}

// ---- Aggregate: 8 nodes/wave, 8 lanes x uint4 per node -------------------
// R2: two-batch software pipeline (u0/u1), 8-16 gathers in flight per wave;
// A,B accumulator pair (fp32 add chain depth 4 per batch, hidden by loads);
// __launch_bounds__(256,4) pins >=4 waves/SIMD (VGPR <= 128).
template <int RELU>
__global__ void __launch_bounds__(256, 4) k_agg(const unsigned short* __restrict__ g16,
                                                const int* __restrict__ col,
                                                const int* __restrict__ rp,
                                                const int* __restrict__ dega,
                                                const float* __restrict__ dis,
                                                const float* __restrict__ bias,
                                                float* __restrict__ out, int n) {
    int lane = threadIdx.x & 63;
    int wv = (blockIdx.x << 2) | (threadIdx.x >> 6);   // global wave id
    int sub = lane >> 3;               // 0..7 : node within wave
    int fl  = lane & 7;                // 0..7 : 8-feat group
    int base = wv << 3;
    if (base >= n) return;             // wave-uniform
    int node = base + sub;
    int nd = min(node, n - 1);
    int start = rp[nd];
    int deg = (node < n) ? dega[nd] : 0;
    int dm = max(deg, __shfl_xor(deg, 8));
    dm = max(dm, __shfl_xor(dm, 16));
    dm = max(dm, __shfl_xor(dm, 32));  // wave max deg

    uint4 us = *((const uint4*)(g16 + ((size_t)nd << 6)) + fl);   // self row
    float A[8], B[8];
    A[0] = blo(us.x); A[1] = bhi(us.x); A[2] = blo(us.y); A[3] = bhi(us.y);
    A[4] = blo(us.z); A[5] = bhi(us.z); A[6] = blo(us.w); A[7] = bhi(us.w);
#pragma unroll
    for (int j = 0; j < 8; ++j) B[j] = 0.f;

    int sb = sub << 3;
    uint4 u0[8], u1[8];

    auto ISSUE = [&](uint4* u, int c) {
        int r = deg - c;               // per-node remaining
        int cv = 0;
        if (fl < r) cv = col[start + c + fl];
        int rr[8];
#pragma unroll
        for (int i = 0; i < 8; ++i) rr[i] = __shfl(cv, sb + i);
#pragma unroll
        for (int i = 0; i < 8; ++i)
            if (i < r) u[i] = *((const uint4*)(g16 + ((size_t)rr[i] << 6)) + fl);
    };
    auto ACCUM = [&](const uint4* u, int c) {
        int r = deg - c;
#pragma unroll
        for (int i = 0; i < 8; ++i) {
            if (i < r) {
                float* T = (i & 1) ? B : A;
                T[0] += blo(u[i].x); T[1] += bhi(u[i].x);
                T[2] += blo(u[i].y); T[3] += bhi(u[i].y);
                T[4] += blo(u[i].z); T[5] += bhi(u[i].z);
                T[6] += blo(u[i].w); T[7] += bhi(u[i].w);
            }
        }
    };

    ISSUE(u0, 0);
    for (int c = 0; c < dm; c += 16) {         // dm wave-uniform -> no divergence
        if (c + 8 < dm) ISSUE(u1, c + 8);      // overlaps ACCUM(u0)
        ACCUM(u0, c);                           // waits vmcnt(8): u1 stays in flight
        if (c + 16 < dm) ISSUE(u0, c + 16);    // overlaps ACCUM(u1)
        if (c + 8 < dm) ACCUM(u1, c + 8);
    }

    float s = dis[nd];
    float4 bv0 = ((const float4*)bias)[fl * 2];
    float4 bv1 = ((const float4*)bias)[fl * 2 + 1];
    float r[8];
#pragma unroll
    for (int j = 0; j < 8; ++j) r[j] = A[j] + B[j];
    float4 o0, o1;
    o0.x = fmaf(s, r[0], bv0.x); o0.y = fmaf(s, r[1], bv0.y);
    o0.z = fmaf(s, r[2], bv0.z); o0.w = fmaf(s, r[3], bv0.w);
    o1.x = fmaf(s, r[4], bv1.x); o1.y = fmaf(s, r[5], bv1.y);
    o1.z = fmaf(s, r[6], bv1.z); o1.w = fmaf(s, r[7], bv1.w);
    if (RELU) {
        o0.x = fmaxf(o0.x, 0.f); o0.y = fmaxf(o0.y, 0.f);
        o0.z = fmaxf(o0.z, 0.f); o0.w = fmaxf(o0.w, 0.f);
        o1.x = fmaxf(o1.x, 0.f); o1.y = fmaxf(o1.y, 0.f);
        o1.z = fmaxf(o1.z, 0.f); o1.w = fmaxf(o1.w, 0.f);
    }
    if (node < n) {
        float4* op = (float4*)(out + ((size_t)node << 6)) + fl * 2;
        op[0] = o0;
        op[1] = o1;
    }
}

extern "C" void kernel_launch(void* const* d_in, const int* in_sizes, int n_in,
                              void* d_out, int out_size, void* d_ws, size_t ws_size,
                              hipStream_t stream) {
    const float* x  = (const float*)d_in[0];
    const int*   ei = (const int*)d_in[1];
    const float* W1 = (const float*)d_in[2];
    const float* b1 = (const float*)d_in[3];
    const float* W2 = (const float*)d_in[4];
    const float* b2 = (const float*)d_in[5];
    float* out = (float*)d_out;

    const int N = in_sizes[0] / 64;
    const int E = in_sizes[1] / 2;
    const int NB = (N + BK_NODES - 1) >> BK_SHIFT;
    const int nstrips = (N + 15) >> 4;
    const int* src = ei;
    const int* dst = ei + E;

    char* ws = (char*)d_ws;
    size_t off = 0;
    auto alloc = [&](size_t bytes) -> void* {
        void* p = ws + off;
        off = (off + bytes + 255) & ~(size_t)255;
        return p;
    };
    int*            gcursor = (int*)alloc((size_t)NB * 4);
    int*            rp      = (int*)alloc((size_t)N * 4);
    int*            dega    = (int*)alloc((size_t)N * 4);
    float*          dis     = (float*)alloc((size_t)N * 4);
    unsigned*       packed  = (unsigned*)alloc((size_t)NB * CAP * 4);
    int*            col     = (int*)alloc((size_t)NB * CAP * 4);
    unsigned short* g16     = (unsigned short*)alloc((size_t)N * 64 * 2);
    float*          h       = (float*)alloc((size_t)N * 64 * 4);
    (void)ws_size;

    k_init<<<1, 256, 0, stream>>>(gcursor, NB);
    k_bscatter<<<(E + EPB - 1) / EPB, 256, 0, stream>>>(src, dst, gcursor, packed, E, NB);
    k_build<<<NB, 512, 0, stream>>>(packed, gcursor, rp, dega, dis, col, N);

    // Layer 1
    k_gemm_mfma<<<782, 256, 0, stream>>>(x, W1, dis, g16, N, nstrips);
    k_agg<1><<<(N + 31) / 32, 256, 0, stream>>>(g16, col, rp, dega, dis, b1, h, N);
    // Layer 2
    k_gemm_mfma<<<782, 256, 0, stream>>>(h, W2, dis, g16, N, nstrips);
    k_agg<0><<<(N + 31) / 32, 256, 0, stream>>>(g16, col, rp, dega, dis, b2, out, N);
}

// Round 3
// 199.283 us; speedup vs baseline: 1.2839x; 1.0456x over previous
//
#include <hip/hip_runtime.h>
#include <cstdint>
#include <cstddef>

// ---------------------------------------------------------------------------
// GCN 2-layer, N=100k nodes, E=1.6M edges, F=64, fp32 in/out.
//
//   dis[n] = rsqrt(in_deg[n]+1)            (self-loop folded in analytically)
//   g = bf16( (X @ W1) * dis[row] )        GEMM via MFMA, split-bf16 x3
//   h = relu( dis * (gather-sum g) + b1 )  per-node, in registers
//   g' = bf16( (h @ W2) * dis )            FUSED MFMA epilogue in agg1:
//                                          h rows -> LDS -> 12 MFMA/wave
//   out = dis * (gather-sum g') + b2
//
// R3: R1's fusion retried with the failure modes fixed. R1 used a per-lane
// VALU epilogue (128 LDS reads + 64 shfl serial) and VGPR 132 -> 3 waves/SIMD.
// Now: h -> LDS (stride 68 to spread banks), one __syncthreads, MFMA epilogue
// with the same split-bf16x3 path as k_gemm_mfma (bitwise-identical tile math
// -> absmax unchanged). Gather regs die before epilogue frags are built, so
// peak VGPR stays in the gather phase; __launch_bounds__(256,4) pins <=128.
// R2 lesson kept: no manual gather pipelining (compiler already hoists the 8
// independent row loads; the memory system, not issue depth, is the limit).
// ---------------------------------------------------------------------------

#define BK_SHIFT 9                 // 512 nodes per bucket
#define BK_NODES 512
#define EPB 8192                   // edges per scatter block
#define CAP 12288                  // padded bucket capacity (slots)
#define NBMAX 256                  // max buckets (N<=131072 -> NB<=256)

typedef short bf16x8 __attribute__((ext_vector_type(8)));
typedef float f32x4  __attribute__((ext_vector_type(4)));

static __device__ __forceinline__ unsigned short f2b(float f) {
    unsigned x = __float_as_uint(f);
    unsigned r = (x + 0x7FFFu + ((x >> 16) & 1u)) >> 16;   // RNE
    return (unsigned short)r;
}
static __device__ __forceinline__ float blo(unsigned u) {
    return __uint_as_float(u << 16);
}
static __device__ __forceinline__ float bhi(unsigned u) {
    return __uint_as_float(u & 0xFFFF0000u);
}
static __device__ __forceinline__ void splitbf(float x, short& hi, short& lo) {
    unsigned short h = f2b(x);
    hi = (short)h;
    float r = x - __uint_as_float((unsigned)h << 16);
    lo = (short)f2b(r);
}

// ---- init: gcursor[b] = b*CAP --------------------------------------------
__global__ void k_init(int* __restrict__ gcursor, int NB) {
    int t = threadIdx.x;
    if (t < NB) gcursor[t] = t * CAP;
}

// ---- scatter edges into padded bucket windows, packed uint32 --------------
// pack = src (17 bits) | dst_local (9 bits) << 17   (N <= 131072)
// Assumes E % 4 == 0 (E=1.6M). 8192 edges/block; loads batched for ILP.
__global__ void __launch_bounds__(256) k_bscatter(const int* __restrict__ src,
                                                  const int* __restrict__ dst,
                                                  int* __restrict__ gcursor,
                                                  unsigned* __restrict__ packed,
                                                  int E, int NB) {
    __shared__ int hist[NBMAX];
    __shared__ int base[NBMAX];
    int t = threadIdx.x;
    for (int i = t; i < NB; i += 256) hist[i] = 0;
    __syncthreads();
    int e0 = blockIdx.x * EPB;
    int e1 = min(e0 + EPB, E);
    // phase 1: block histogram (8 int4 loads batched, then atomics)
    int4 dv[8];
    int kd[8];
#pragma unroll
    for (int k = 0; k < 8; ++k) {
        int e = e0 + t * 4 + k * 1024;
        kd[k] = (e + 3 < e1) ? 1 : 0;
        if (kd[k]) dv[k] = *(const int4*)(dst + e);
    }
#pragma unroll
    for (int k = 0; k < 8; ++k) {
        if (kd[k]) {
            atomicAdd(&hist[dv[k].x >> BK_SHIFT], 1);
            atomicAdd(&hist[dv[k].y >> BK_SHIFT], 1);
            atomicAdd(&hist[dv[k].z >> BK_SHIFT], 1);
            atomicAdd(&hist[dv[k].w >> BK_SHIFT], 1);
        }
    }
    __syncthreads();
    // phase 2: reserve chunk in each bucket's padded window
    for (int i = t; i < NB; i += 256) {
        int c = hist[i];
        base[i] = c ? atomicAdd(&gcursor[i], c) : 0;
        hist[i] = 0;
    }
    __syncthreads();
    // phase 3: scatter (batched src loads; dst re-used from regs)
    int4 sv[8];
#pragma unroll
    for (int k = 0; k < 8; ++k) {
        int e = e0 + t * 4 + k * 1024;
        if (kd[k]) sv[k] = *(const int4*)(src + e);
    }
#pragma unroll
    for (int k = 0; k < 8; ++k) {
        if (kd[k]) {
            int b0 = dv[k].x >> BK_SHIFT;
            int p0 = base[b0] + atomicAdd(&hist[b0], 1);
            packed[p0] = (unsigned)sv[k].x | (((unsigned)dv[k].x & (BK_NODES - 1)) << 17);
            int b1 = dv[k].y >> BK_SHIFT;
            int p1 = base[b1] + atomicAdd(&hist[b1], 1);
            packed[p1] = (unsigned)sv[k].y | (((unsigned)dv[k].y & (BK_NODES - 1)) << 17);
            int b2 = dv[k].z >> BK_SHIFT;
            int p2 = base[b2] + atomicAdd(&hist[b2], 1);
            packed[p2] = (unsigned)sv[k].z | (((unsigned)dv[k].z & (BK_NODES - 1)) << 17);
            int b3 = dv[k].w >> BK_SHIFT;
            int p3 = base[b3] + atomicAdd(&hist[b3], 1);
            packed[p3] = (unsigned)sv[k].w | (((unsigned)dv[k].w & (BK_NODES - 1)) << 17);
        }
    }
}

// ---- per-bucket CSR build (one block of 512 per bucket) -------------------
__global__ void __launch_bounds__(512) k_build(const unsigned* __restrict__ packed,
                                               const int* __restrict__ gcursor,
                                               int* __restrict__ rp,
                                               int* __restrict__ dega,
                                               float* __restrict__ dis,
                                               int* __restrict__ col, int N) {
    __shared__ int cnt_s[BK_NODES];
    __shared__ int tmp[BK_NODES];
    int b = blockIdx.x;
    int t = threadIdx.x;
    int node0 = b << BK_SHIFT;
    int nnode = min(BK_NODES, N - node0);
    int e0 = b * CAP;
    int e1 = gcursor[b];               // final cursor = e0 + count
    cnt_s[t] = 0;
    __syncthreads();
    for (int e = e0 + t * 4; e < e1; e += 2048) {
        int m = e1 - e; m = m > 4 ? 4 : m;
        unsigned p0 = packed[e];
        unsigned p1 = (m > 1) ? packed[e + 1] : 0;
        unsigned p2 = (m > 2) ? packed[e + 2] : 0;
        unsigned p3 = (m > 3) ? packed[e + 3] : 0;
        atomicAdd(&cnt_s[p0 >> 17], 1);
        if (m > 1) atomicAdd(&cnt_s[p1 >> 17], 1);
        if (m > 2) atomicAdd(&cnt_s[p2 >> 17], 1);
        if (m > 3) atomicAdd(&cnt_s[p3 >> 17], 1);
    }
    __syncthreads();
    int v = cnt_s[t];
    tmp[t] = v;
    __syncthreads();
    for (int off = 1; off < BK_NODES; off <<= 1) {
        int a = (t >= off) ? tmp[t - off] : 0;
        __syncthreads();
        tmp[t] += a;
        __syncthreads();
    }
    int excl = tmp[t] - v;
    if (t < nnode) {
        rp[node0 + t] = e0 + excl;
        dega[node0 + t] = v;
        dis[node0 + t] = rsqrtf((float)(v + 1));
    }
    __syncthreads();
    cnt_s[t] = excl;                   // reuse as local cursor
    __syncthreads();
    for (int e = e0 + t * 4; e < e1; e += 2048) {
        int m = e1 - e; m = m > 4 ? 4 : m;
        unsigned p0 = packed[e];
        unsigned p1 = (m > 1) ? packed[e + 1] : 0;
        unsigned p2 = (m > 2) ? packed[e + 2] : 0;
        unsigned p3 = (m > 3) ? packed[e + 3] : 0;
        int pos0 = atomicAdd(&cnt_s[p0 >> 17], 1);
        col[e0 + pos0] = (int)(p0 & 0x1FFFFu);
        if (m > 1) { int pos = atomicAdd(&cnt_s[p1 >> 17], 1); col[e0 + pos] = (int)(p1 & 0x1FFFFu); }
        if (m > 2) { int pos = atomicAdd(&cnt_s[p2 >> 17], 1); col[e0 + pos] = (int)(p2 & 0x1FFFFu); }
        if (m > 3) { int pos = atomicAdd(&cnt_s[p3 >> 17], 1); col[e0 + pos] = (int)(p3 & 0x1FFFFu); }
    }
}

// ---- GEMM via MFMA: g16[row] = bf16( (X[row] @ W) * dis[row] ) ------------
// Layouts (measured, learn_hip m89/m91/m120):
//   A[m=lane&15][k=quad*8+j]   B[k=quad*8+j][n=lane&15]
//   C: col=lane&15, row=quad*4+reg
__global__ void __launch_bounds__(256) k_gemm_mfma(const float* __restrict__ X,
                                                   const float* __restrict__ W,
                                                   const float* __restrict__ dis,
                                                   unsigned short* __restrict__ g16,
                                                   int n, int nstrips) {
    __shared__ float Ws[4096];     // 64x64 fp32 = 16 KB
    int t = threadIdx.x;
    {
        const float4* W4 = (const float4*)W;
        float4* S4 = (float4*)Ws;
#pragma unroll
        for (int i = 0; i < 4; ++i) S4[t + i * 256] = W4[t + i * 256];
    }
    __syncthreads();
    int wid  = t >> 6;
    int lane = t & 63;
    int quad = lane >> 4;
    int fl   = lane & 15;

    bf16x8 Bh[4][2], Bl[4][2];
#pragma unroll
    for (int tt = 0; tt < 4; ++tt)
#pragma unroll
        for (int c = 0; c < 2; ++c)
#pragma unroll
            for (int j = 0; j < 8; ++j) {
                float w = Ws[(c * 32 + quad * 8 + j) * 64 + tt * 16 + fl];
                short hi, lo;
                splitbf(w, hi, lo);
                Bh[tt][c][j] = hi;
                Bl[tt][c][j] = lo;
            }

    for (int s = blockIdx.x * 4 + wid; s < nstrips; s += gridDim.x * 4) {
        int row0 = s << 4;
        const float4* xp = (const float4*)(X + ((size_t)(row0 + fl) << 6));
        bf16x8 Ah[2], Al[2];
#pragma unroll
        for (int c = 0; c < 2; ++c) {
            float4 a = xp[c * 8 + quad * 2];
            float4 b = xp[c * 8 + quad * 2 + 1];
            float xs[8] = {a.x, a.y, a.z, a.w, b.x, b.y, b.z, b.w};
#pragma unroll
            for (int j = 0; j < 8; ++j) {
                short hi, lo;
                splitbf(xs[j], hi, lo);
                Ah[c][j] = hi;
                Al[c][j] = lo;
            }
        }
        f32x4 acc[4];
#pragma unroll
        for (int tt = 0; tt < 4; ++tt) acc[tt] = (f32x4){0.f, 0.f, 0.f, 0.f};
#pragma unroll
        for (int tt = 0; tt < 4; ++tt) {
#pragma unroll
            for (int c = 0; c < 2; ++c) {
                acc[tt] = __builtin_amdgcn_mfma_f32_16x16x32_bf16(Ah[c], Bh[tt][c], acc[tt], 0, 0, 0);
                acc[tt] = __builtin_amdgcn_mfma_f32_16x16x32_bf16(Al[c], Bh[tt][c], acc[tt], 0, 0, 0);
                acc[tt] = __builtin_amdgcn_mfma_f32_16x16x32_bf16(Ah[c], Bl[tt][c], acc[tt], 0, 0, 0);
            }
        }
        float4 dv = *(const float4*)(dis + row0 + quad * 4);
        float ds4[4] = {dv.x, dv.y, dv.z, dv.w};
#pragma unroll
        for (int tt = 0; tt < 4; ++tt) {
#pragma unroll
            for (int r = 0; r < 4; ++r) {
                int row = row0 + quad * 4 + r;
                float v = acc[tt][r] * ds4[r];
                g16[(size_t)row * 64 + tt * 16 + fl] = f2b(v);
            }
        }
    }
}

// ---- Aggregate: 8 nodes/wave, 8 lanes x uint4 per node, 8 loads in flight -
// (exact R0 structure: best-measured gather)
template <int RELU>
__global__ void __launch_bounds__(256) k_agg(const unsigned short* __restrict__ g16,
                                             const int* __restrict__ col,
                                             const int* __restrict__ rp,
                                             const int* __restrict__ dega,
                                             const float* __restrict__ dis,
                                             const float* __restrict__ bias,
                                             float* __restrict__ out, int n) {
    int lane = threadIdx.x & 63;
    int wv = (blockIdx.x << 2) | (threadIdx.x >> 6);   // global wave id
    int sub = lane >> 3;               // 0..7 : node within wave
    int fl  = lane & 7;                // 0..7 : 8-feat group
    int base = wv << 3;
    if (base >= n) return;             // wave-uniform
    int node = base + sub;
    int nd = min(node, n - 1);
    int start = rp[nd];
    int deg = (node < n) ? dega[nd] : 0;
    int dm = max(deg, __shfl_xor(deg, 8));
    dm = max(dm, __shfl_xor(dm, 16));
    dm = max(dm, __shfl_xor(dm, 32));  // wave max deg

    uint4 us = *((const uint4*)(g16 + ((size_t)nd << 6)) + fl);   // self row
    float A[8], B[8], C[8], D[8];
    A[0] = blo(us.x); A[1] = bhi(us.x); A[2] = blo(us.y); A[3] = bhi(us.y);
    A[4] = blo(us.z); A[5] = bhi(us.z); A[6] = blo(us.w); A[7] = bhi(us.w);
#pragma unroll
    for (int j = 0; j < 8; ++j) { B[j] = 0.f; C[j] = 0.f; D[j] = 0.f; }

    int sb = sub << 3;
    for (int c = 0; c < dm; c += 8) {
        int rem = deg - c;
        int cv = 0;
        if (fl < rem) cv = col[start + c + fl];
        int rr[8];
#pragma unroll
        for (int i = 0; i < 8; ++i) rr[i] = __shfl(cv, sb + i);
        uint4 u[8];
#pragma unroll
        for (int i = 0; i < 8; ++i)
            if (i < rem) u[i] = *((const uint4*)(g16 + ((size_t)rr[i] << 6)) + fl);
#pragma unroll
        for (int i = 0; i < 8; ++i) {
            if (i < rem) {
                float* T = ((i & 3) == 0) ? A : ((i & 3) == 1) ? B : ((i & 3) == 2) ? C : D;
                T[0] += blo(u[i].x); T[1] += bhi(u[i].x);
                T[2] += blo(u[i].y); T[3] += bhi(u[i].y);
                T[4] += blo(u[i].z); T[5] += bhi(u[i].z);
                T[6] += blo(u[i].w); T[7] += bhi(u[i].w);
            }
        }
    }
    float s = dis[nd];
    float4 bv0 = ((const float4*)bias)[fl * 2];
    float4 bv1 = ((const float4*)bias)[fl * 2 + 1];
    float r[8];
#pragma unroll
    for (int j = 0; j < 8; ++j) r[j] = (A[j] + B[j]) + (C[j] + D[j]);
    float4 o0, o1;
    o0.x = fmaf(s, r[0], bv0.x); o0.y = fmaf(s, r[1], bv0.y);
    o0.z = fmaf(s, r[2], bv0.z); o0.w = fmaf(s, r[3], bv0.w);
    o1.x = fmaf(s, r[4], bv1.x); o1.y = fmaf(s, r[5], bv1.y);
    o1.z = fmaf(s, r[6], bv1.z); o1.w = fmaf(s, r[7], bv1.w);
    if (RELU) {
        o0.x = fmaxf(o0.x, 0.f); o0.y = fmaxf(o0.y, 0.f);
        o0.z = fmaxf(o0.z, 0.f); o0.w = fmaxf(o0.w, 0.f);
        o1.x = fmaxf(o1.x, 0.f); o1.y = fmaxf(o1.y, 0.f);
        o1.z = fmaxf(o1.z, 0.f); o1.w = fmaxf(o1.w, 0.f);
    }
    if (node < n) {
        float4* op = (float4*)(out + ((size_t)node << 6)) + fl * 2;
        op[0] = o0;
        op[1] = o1;
    }
}

// ---- Fused aggregate(L1)+relu  ->  LDS  ->  MFMA (h @ W2) * dis -> bf16 ---
// Gather phase identical to R0's k_agg<1>, but h rows go to LDS (stride 68
// to spread banks) instead of HBM. After one __syncthreads, the 4 waves
// compute the block's 32x64 h@W2 with 12 MFMAs each, using the exact
// split-bf16x3 + accumulate order of k_gemm_mfma (bitwise-identical tile
// math -> absmax unchanged). Gather registers die before the epilogue's
// fragments are built from LDS, so peak VGPR stays in the gather phase.
__global__ void __launch_bounds__(256, 4) k_agg_gemm2(const unsigned short* __restrict__ g16,
                                                      const int* __restrict__ col,
                                                      const int* __restrict__ rp,
                                                      const int* __restrict__ dega,
                                                      const float* __restrict__ dis,
                                                      const float* __restrict__ bias,
                                                      const float* __restrict__ W2,
                                                      unsigned short* __restrict__ g16b,
                                                      int n) {
    __shared__ float W2s[4096];        // 64x64 fp32 = 16 KB
    __shared__ float hs[32 * 68];      // 32 h rows, stride 68 (bank spread), 8.7 KB
    int t = threadIdx.x;
    {
        const float4* W4 = (const float4*)W2;
        float4* S4 = (float4*)W2s;
#pragma unroll
        for (int i = 0; i < 4; ++i) S4[t + i * 256] = W4[t + i * 256];
    }
    // (W2s consumed only after the __syncthreads below)

    int lane = t & 63;
    int wid  = t >> 6;
    int wv = (blockIdx.x << 2) | wid;
    int sub = lane >> 3;               // 0..7 : node within wave
    int fl  = lane & 7;                // 0..7 : 8-feat group
    int base = wv << 3;
    int node = base + sub;
    int nd = (node < n) ? node : (n - 1);
    int start = rp[nd];
    int deg = (node < n) ? dega[nd] : 0;
    int dm = max(deg, __shfl_xor(deg, 8));
    dm = max(dm, __shfl_xor(dm, 16));
    dm = max(dm, __shfl_xor(dm, 32));  // wave max deg (0 for fully-inactive)

    uint4 us = *((const uint4*)(g16 + ((size_t)nd << 6)) + fl);   // self row
    float A[8], B[8], C[8], D[8];
    A[0] = blo(us.x); A[1] = bhi(us.x); A[2] = blo(us.y); A[3] = bhi(us.y);
    A[4] = blo(us.z); A[5] = bhi(us.z); A[6] = blo(us.w); A[7] = bhi(us.w);
#pragma unroll
    for (int j = 0; j < 8; ++j) { B[j] = 0.f; C[j] = 0.f; D[j] = 0.f; }

    int sb = sub << 3;
    for (int c = 0; c < dm; c += 8) {
        int rem = deg - c;
        int cv = 0;
        if (fl < rem) cv = col[start + c + fl];
        int rr[8];
#pragma unroll
        for (int i = 0; i < 8; ++i) rr[i] = __shfl(cv, sb + i);
        uint4 u[8];
#pragma unroll
        for (int i = 0; i < 8; ++i)
            if (i < rem) u[i] = *((const uint4*)(g16 + ((size_t)rr[i] << 6)) + fl);
#pragma unroll
        for (int i = 0; i < 8; ++i) {
            if (i < rem) {
                float* T = ((i & 3) == 0) ? A : ((i & 3) == 1) ? B : ((i & 3) == 2) ? C : D;
                T[0] += blo(u[i].x); T[1] += bhi(u[i].x);
                T[2] += blo(u[i].y); T[3] += bhi(u[i].y);
                T[4] += blo(u[i].z); T[5] += bhi(u[i].z);
                T[6] += blo(u[i].w); T[7] += bhi(u[i].w);
            }
        }
    }
    // h = relu(dis*agg + b1); this lane holds feats fl*8..fl*8+7 of its node
    {
        float s = dis[nd];
        float4 bv0 = ((const float4*)bias)[fl * 2];
        float4 bv1 = ((const float4*)bias)[fl * 2 + 1];
        float r[8];
#pragma unroll
        for (int j = 0; j < 8; ++j) r[j] = (A[j] + B[j]) + (C[j] + D[j]);
        float4 h0, h1;
        h0.x = fmaxf(fmaf(s, r[0], bv0.x), 0.f);
        h0.y = fmaxf(fmaf(s, r[1], bv0.y), 0.f);
        h0.z = fmaxf(fmaf(s, r[2], bv0.z), 0.f);
        h0.w = fmaxf(fmaf(s, r[3], bv0.w), 0.f);
        h1.x = fmaxf(fmaf(s, r[4], bv1.x), 0.f);
        h1.y = fmaxf(fmaf(s, r[5], bv1.y), 0.f);
        h1.z = fmaxf(fmaf(s, r[6], bv1.z), 0.f);
        h1.w = fmaxf(fmaf(s, r[7], bv1.w), 0.f);
        int lrow = (wid << 3) | sub;   // 0..31 block-local row
        float* hp = &hs[lrow * 68 + fl * 8];   // byte addr % 16 == 0
        *(float4*)hp = h0;
        *(float4*)(hp + 4) = h1;
    }
    __syncthreads();

    // ---- MFMA epilogue: 32x64 = hs @ W2s, 2 row-strips x 4 col-tiles ------
    {
        int quad = lane >> 4;
        int fq   = lane & 15;
        int strip = wid >> 1;          // 0/1 : 16-row strip
        int tbase = (wid & 1) << 1;    // col tiles tbase, tbase+1
        bf16x8 Ah[2], Al[2];
#pragma unroll
        for (int kc = 0; kc < 2; ++kc) {
            const float* hp2 = &hs[(strip * 16 + fq) * 68 + kc * 32 + quad * 8];
            float4 a = *(const float4*)hp2;
            float4 b = *(const float4*)(hp2 + 4);
            float xs[8] = {a.x, a.y, a.z, a.w, b.x, b.y, b.z, b.w};
#pragma unroll
            for (int j = 0; j < 8; ++j) {
                short hi, lo;
                splitbf(xs[j], hi, lo);
                Ah[kc][j] = hi;
                Al[kc][j] = lo;
            }
        }
        f32x4 acc[2];
        acc[0] = (f32x4){0.f, 0.f, 0.f, 0.f};
        acc[1] = (f32x4){0.f, 0.f, 0.f, 0.f};
#pragma unroll
        for (int tt = 0; tt < 2; ++tt) {
#pragma unroll
            for (int kc = 0; kc < 2; ++kc) {
                bf16x8 Bh, Bl;
#pragma unroll
                for (int j = 0; j < 8; ++j) {
                    float w = W2s[(kc * 32 + quad * 8 + j) * 64 + (tbase + tt) * 16 + fq];
                    short hi, lo;
                    splitbf(w, hi, lo);
                    Bh[j] = hi;
                    Bl[j] = lo;
                }
                acc[tt] = __builtin_amdgcn_mfma_f32_16x16x32_bf16(Ah[kc], Bh, acc[tt], 0, 0, 0);
                acc[tt] = __builtin_amdgcn_mfma_f32_16x16x32_bf16(Al[kc], Bh, acc[tt], 0, 0, 0);
                acc[tt] = __builtin_amdgcn_mfma_f32_16x16x32_bf16(Ah[kc], Bl, acc[tt], 0, 0, 0);
            }
        }
        int row0 = (blockIdx.x << 5) + strip * 16 + quad * 4;
        float d4[4];
        if (row0 + 3 < n) {
            float4 dv = *(const float4*)(dis + row0);
            d4[0] = dv.x; d4[1] = dv.y; d4[2] = dv.z; d4[3] = dv.w;
        } else {
#pragma unroll
            for (int r2 = 0; r2 < 4; ++r2) d4[r2] = (row0 + r2 < n) ? dis[row0 + r2] : 0.f;
        }
#pragma unroll
        for (int tt = 0; tt < 2; ++tt) {
#pragma unroll
            for (int r2 = 0; r2 < 4; ++r2) {
                int row = row0 + r2;
                if (row < n)
                    g16b[(size_t)row * 64 + (tbase + tt) * 16 + fq] = f2b(acc[tt][r2] * d4[r2]);
            }
        }
    }
}

extern "C" void kernel_launch(void* const* d_in, const int* in_sizes, int n_in,
                              void* d_out, int out_size, void* d_ws, size_t ws_size,
                              hipStream_t stream) {
    const float* x  = (const float*)d_in[0];
    const int*   ei = (const int*)d_in[1];
    const float* W1 = (const float*)d_in[2];
    const float* b1 = (const float*)d_in[3];
    const float* W2 = (const float*)d_in[4];
    const float* b2 = (const float*)d_in[5];
    float* out = (float*)d_out;

    const int N = in_sizes[0] / 64;
    const int E = in_sizes[1] / 2;
    const int NB = (N + BK_NODES - 1) >> BK_SHIFT;
    const int nstrips = (N + 15) >> 4;
    const int* src = ei;
    const int* dst = ei + E;

    char* ws = (char*)d_ws;
    size_t off = 0;
    auto alloc = [&](size_t bytes) -> void* {
        void* p = ws + off;
        off = (off + bytes + 255) & ~(size_t)255;
        return p;
    };
    int*            gcursor = (int*)alloc((size_t)NB * 4);
    int*            rp      = (int*)alloc((size_t)N * 4);
    int*            dega    = (int*)alloc((size_t)N * 4);
    float*          dis     = (float*)alloc((size_t)N * 4);
    unsigned*       packed  = (unsigned*)alloc((size_t)NB * CAP * 4);
    int*            col     = (int*)alloc((size_t)NB * CAP * 4);
    unsigned short* g16     = (unsigned short*)alloc((size_t)N * 64 * 2);
    unsigned short* g16b    = (unsigned short*)alloc((size_t)N * 64 * 2);
    (void)ws_size;

    k_init<<<1, 256, 0, stream>>>(gcursor, NB);
    k_bscatter<<<(E + EPB - 1) / EPB, 256, 0, stream>>>(src, dst, gcursor, packed, E, NB);
    k_build<<<NB, 512, 0, stream>>>(packed, gcursor, rp, dega, dis, col, N);

    // Layer 1 GEMM (MFMA), fused agg1+relu+GEMM2 -> g16b, then agg2 -> out
    k_gemm_mfma<<<782, 256, 0, stream>>>(x, W1, dis, g16, N, nstrips);
    k_agg_gemm2<<<(N + 31) / 32, 256, 0, stream>>>(g16, col, rp, dega, dis, b1, W2, g16b, N);
    k_agg<0><<<(N + 31) / 32, 256, 0, stream>>>(g16b, col, rp, dega, dis, b2, out, N);
}